// Round 1
// baseline (343.231 us; speedup 1.0000x reference)
//
#include <hip/hip_runtime.h>

// Problem constants (from reference)
#define D        128      // EMBEDDING_DIM
#define KCODES   2048     // NUM_EMBEDDINGS
#define NROWS    32768    // BATCH * FEATURE_LENGTH / D
#define BATCH    8192

#define MT    128         // rows per block tile
#define NT    128         // codewords per tile
#define DPAD  132         // padded row stride (floats) to break bank conflicts

// ---------------------------------------------------------------------------
// Kernel 0: ||W_k||^2 per codeword. 2048 blocks x 64 threads (one wave/code).
// ---------------------------------------------------------------------------
__global__ void wnorm_kernel(const float* __restrict__ W, float* __restrict__ wnorm) {
    int k = blockIdx.x;
    int l = threadIdx.x;              // 0..63
    float2 v = reinterpret_cast<const float2*>(W + (size_t)k * D)[l];
    float s = v.x * v.x + v.y * v.y;
    #pragma unroll
    for (int off = 32; off; off >>= 1) s += __shfl_down(s, off);
    if (l == 0) wnorm[k] = s;
}

// ---------------------------------------------------------------------------
// Kernel 1: fused scores + argmin.
// Block: 256 threads. Tile: 128 rows x 128 codewords, contraction d=128 fully
// resident in LDS for f; W streamed in 16 tiles of 128 codewords.
// Each thread: 8 rows x 8 cols register micro-tile (interleaved by 16).
// ---------------------------------------------------------------------------
extern "C" __global__ void __launch_bounds__(256, 1)
vq_argmin(const float* __restrict__ f, const float* __restrict__ W,
          const float* __restrict__ wnorm, int* __restrict__ bestIdx) {
    extern __shared__ float lds[];
    float* sf = lds;               // [MT][DPAD]
    float* sw = lds + MT * DPAD;   // [NT][DPAD]

    const int tid = threadIdx.x;
    const int tx  = tid & 15;      // column group 0..15
    const int ty  = tid >> 4;      // row group 0..15
    const int rowBase = blockIdx.x * MT;

    // ---- stage f tile (128 rows x 128 floats = 64 KB), coalesced float4 ----
    #pragma unroll 4
    for (int it = 0; it < 16; ++it) {
        int fi = it * 256 + tid;               // float4 index in 128x32 grid
        int r  = fi >> 5;
        int c4 = (fi & 31) << 2;
        float4 v = *reinterpret_cast<const float4*>(f + (size_t)(rowBase + r) * D + c4);
        *reinterpret_cast<float4*>(sf + r * DPAD + c4) = v;
    }

    float best[8];
    int   bidx[8];
    #pragma unroll
    for (int i = 0; i < 8; ++i) { best[i] = 3.4e38f; bidx[i] = 0; }

    for (int t = 0; t < KCODES / NT; ++t) {
        __syncthreads();   // previous tile's readers done (also fences f staging)
        // ---- stage W tile (128 codewords x 128 floats) ----
        #pragma unroll 4
        for (int it = 0; it < 16; ++it) {
            int fi = it * 256 + tid;
            int r  = fi >> 5;
            int c4 = (fi & 31) << 2;
            float4 v = *reinterpret_cast<const float4*>(W + (size_t)(t * NT + r) * D + c4);
            *reinterpret_cast<float4*>(sw + r * DPAD + c4) = v;
        }
        __syncthreads();

        // ---- 8x8 micro-tile over d=128 ----
        float acc[8][8];
        #pragma unroll
        for (int i = 0; i < 8; ++i)
            #pragma unroll
            for (int j = 0; j < 8; ++j) acc[i][j] = 0.0f;

        for (int dd = 0; dd < D; dd += 4) {
            float4 ff[8], ww[8];
            #pragma unroll
            for (int i = 0; i < 8; ++i)
                ff[i] = *reinterpret_cast<const float4*>(sf + (ty + 16 * i) * DPAD + dd);
            #pragma unroll
            for (int j = 0; j < 8; ++j)
                ww[j] = *reinterpret_cast<const float4*>(sw + (tx + 16 * j) * DPAD + dd);
            #pragma unroll
            for (int i = 0; i < 8; ++i)
                #pragma unroll
                for (int j = 0; j < 8; ++j)
                    acc[i][j] += ff[i].x * ww[j].x + ff[i].y * ww[j].y
                               + ff[i].z * ww[j].z + ff[i].w * ww[j].w;
        }

        // ---- fold into running argmin: s = ||W_c||^2 - 2*dot ----
        #pragma unroll
        for (int j = 0; j < 8; ++j) {
            int c = t * NT + tx + 16 * j;      // ascending within thread
            float wn = wnorm[c];
            #pragma unroll
            for (int i = 0; i < 8; ++i) {
                float s = wn - 2.0f * acc[i][j];
                if (s < best[i]) { best[i] = s; bidx[i] = c; }
            }
        }
    }

    // ---- cross-thread reduce: 16 threads (tx groups) share each row ----
    __syncthreads();
    float* rs = lds;                         // [16][MT]
    int*   ri = reinterpret_cast<int*>(lds + 16 * MT);   // [16][MT]
    #pragma unroll
    for (int i = 0; i < 8; ++i) {
        int r = ty + 16 * i;
        rs[tx * MT + r] = best[i];
        ri[tx * MT + r] = bidx[i];
    }
    __syncthreads();
    if (tid < MT) {
        float bs = rs[tid];
        int   bi = ri[tid];
        for (int t2 = 1; t2 < 16; ++t2) {
            float s2 = rs[t2 * MT + tid];
            int   i2 = ri[t2 * MT + tid];
            if (s2 < bs || (s2 == bs && i2 < bi)) { bs = s2; bi = i2; }
        }
        bestIdx[rowBase + tid] = bi;
    }
}

// ---------------------------------------------------------------------------
// Kernel 2: gather W[j], write out, compute loss per batch element.
// One block (4 waves) per batch row; one wave per d=128 sub-row.
// ---------------------------------------------------------------------------
__global__ void gather_kernel(const float* __restrict__ f, const float* __restrict__ W,
                              const int* __restrict__ bestIdx,
                              float* __restrict__ loss, float* __restrict__ outv) {
    int b  = blockIdx.x;
    int wv = threadIdx.x >> 6;   // 0..3
    int l  = threadIdx.x & 63;
    int n  = b * 4 + wv;
    int j  = bestIdx[n];
    float2 fv = reinterpret_cast<const float2*>(f + (size_t)n * D)[l];
    float2 wj = reinterpret_cast<const float2*>(W + (size_t)j * D)[l];
    reinterpret_cast<float2*>(outv + (size_t)n * D)[l] = wj;
    float dx = fv.x - wj.x, dy = fv.y - wj.y;
    float s = dx * dx + dy * dy;
    #pragma unroll
    for (int off = 32; off; off >>= 1) s += __shfl_down(s, off);
    __shared__ float ls[4];
    if (l == 0) ls[wv] = s;
    __syncthreads();
    if (threadIdx.x == 0)
        loss[b] = 1.25f * 0.25f * (ls[0] + ls[1] + ls[2] + ls[3]);
}

// ---------------------------------------------------------------------------
extern "C" void kernel_launch(void* const* d_in, const int* in_sizes, int n_in,
                              void* d_out, int out_size, void* d_ws, size_t ws_size,
                              hipStream_t stream) {
    const float* f = (const float*)d_in[0];   // [8192,512] -> rows of 128
    const float* W = (const float*)d_in[1];   // [2048,128]

    float* loss = (float*)d_out;              // [8192]
    float* outv = (float*)d_out + BATCH;      // [8192*512]

    float* wnorm   = (float*)d_ws;                        // 2048 floats
    int*   bestIdx = (int*)((char*)d_ws + 8192);          // 32768 ints

    wnorm_kernel<<<KCODES, 64, 0, stream>>>(W, wnorm);

    size_t ldsBytes = (size_t)(MT + NT) * DPAD * sizeof(float);   // 135168 B
    hipLaunchKernelGGL(vq_argmin, dim3(NROWS / MT), dim3(256), ldsBytes, stream,
                       f, W, wnorm, bestIdx);

    gather_kernel<<<BATCH, 256, 0, stream>>>(f, W, bestIdx, loss, outv);
}

// Round 2
// 170.844 us; speedup vs baseline: 2.0090x; 2.0090x over previous
//
#include <hip/hip_runtime.h>

#define D        128
#define KCODES   2048
#define NROWS    32768
#define BATCH    8192
#define MT       128      // rows per block in vq_argmin

typedef _Float16 f16x8 __attribute__((ext_vector_type(8)));
typedef float    f32x16 __attribute__((ext_vector_type(16)));

#define MFMA(a, b, c) __builtin_amdgcn_mfma_f32_32x32x16_f16((a), (b), (c), 0, 0, 0)

static __device__ __forceinline__ f32x16 zero16() {
    f32x16 z;
#pragma unroll
    for (int i = 0; i < 16; ++i) z[i] = 0.0f;
    return z;
}

// ---------------------------------------------------------------------------
// Kernel A: convert W -> (wh, wl) fp16 hi/lo in FRAGMENT-LINEAR layout, plus
// exact fp32 ||W_k||^2.  Fragment unit for code-block n0 (32 codes), kstep ks
// (16 k's): lane l holds W[n0*32 + (l&31)][ks*16 + (l>>5)*8 + j], j=0..7.
// Stored at f16x8 index ((n0*8 + ks)*64 + l).  lo is pre-scaled by 2048.
// ---------------------------------------------------------------------------
__global__ void wconv_kernel(const float* __restrict__ W,
                             _Float16* __restrict__ whf, _Float16* __restrict__ wlf,
                             float* __restrict__ wnorm) {
    int gid = blockIdx.x * 256 + threadIdx.x;    // 32768 = 2048 codes x 16 slots
    int n = gid >> 4, s = gid & 15;
    const float4* src = (const float4*)(W + (size_t)n * D + s * 8);
    float4 a = src[0], b = src[1];
    float va[8] = {a.x, a.y, a.z, a.w, b.x, b.y, b.z, b.w};
    f16x8 hi, lo;
    float ss = 0.0f;
#pragma unroll
    for (int j = 0; j < 8; ++j) {
        _Float16 h = (_Float16)va[j];
        hi[j] = h;
        lo[j] = (_Float16)((va[j] - (float)h) * 2048.0f);
        ss += va[j] * va[j];
    }
    int ks = s >> 1, sub = s & 1;
    size_t idx = ((size_t)((n >> 5) * 8 + ks) * 64 + sub * 32 + (n & 31));
    ((f16x8*)whf)[idx] = hi;
    ((f16x8*)wlf)[idx] = lo;
    // 16 threads (same wave, 16-aligned) share code n -> wnorm
#pragma unroll
    for (int m = 1; m <= 8; m <<= 1) ss += __shfl_xor(ss, m);
    if (s == 0) wnorm[n] = ss;
}

// ---------------------------------------------------------------------------
// Kernel B: fused MFMA scores + argmin.
// 256 blocks x 512 threads (8 waves, grid 2m x 4n). Block tile: 128 rows.
// f staged inline fp32->fp16 hi/lo into XOR-swizzled LDS (68 KB total).
// Wave tile per code-chunk: 64 rows x 64 codes via 32x32x16 f16 MFMA.
// Running per-lane argmin; one butterfly + LDS fold at the end.
// ---------------------------------------------------------------------------
extern "C" __global__ void __launch_bounds__(512, 2)
vq_argmin(const float* __restrict__ f,
          const _Float16* __restrict__ whf, const _Float16* __restrict__ wlf,
          const float* __restrict__ wnorm, int* __restrict__ bestIdx) {
    extern __shared__ unsigned char lds[];
    // fh: [0,32768) rows r: byte r*256 + (slot ^ (r&15))*16
    // fl: [32768,65536) same layout;  reduce buf at 65536
    float* redS = (float*)(lds + 65536);          // [128][4]
    int*   redC = (int*)(lds + 65536 + 2048);     // [128][4]

    const int tid = threadIdx.x;
    const int rowBase = blockIdx.x * MT;

    // ---- stage f tile: thread -> 32 consecutive floats of one row ----
    {
        int r = tid >> 2, q = tid & 3;
        const float4* src = (const float4*)(f + (size_t)(rowBase + r) * D + q * 32);
        unsigned rx = r & 15;
#pragma unroll
        for (int u = 0; u < 4; ++u) {
            float4 a = src[2 * u], b = src[2 * u + 1];
            float va[8] = {a.x, a.y, a.z, a.w, b.x, b.y, b.z, b.w};
            f16x8 hi, lo;
#pragma unroll
            for (int j = 0; j < 8; ++j) {
                _Float16 h = (_Float16)va[j];
                hi[j] = h;
                lo[j] = (_Float16)((va[j] - (float)h) * 2048.0f);
            }
            unsigned sp = (unsigned)(q * 4 + u) ^ rx;
            *(f16x8*)(lds + r * 256 + sp * 16) = hi;
            *(f16x8*)(lds + 32768 + r * 256 + sp * 16) = lo;
        }
    }
    __syncthreads();

    const int w   = tid >> 6;          // wave 0..7
    const int l   = tid & 63;
    const int wm  = w >> 2;            // 0..1  (m half)
    const int wn  = w & 3;             // 0..3  (n quarter)
    const int l31 = l & 31;
    const int lh  = l >> 5;

    const int rowA0 = wm * 64 + l31;       // i=0 frag row
    const int rowA1 = rowA0 + 32;          // i=1 frag row
    const unsigned swz0 = (unsigned)(rowA0 & 15);   // == l&15
    const unsigned swz1 = (unsigned)(rowA1 & 15);

    const f16x8* whv = (const f16x8*)whf;
    const f16x8* wlv = (const f16x8*)wlf;

    float bestS[32];
    int   bestC[32];
#pragma unroll
    for (int e = 0; e < 32; ++e) { bestS[e] = 3.4e38f; bestC[e] = 0; }

#define FH(rowA, swz, sl) (*(const f16x8*)(lds +         (rowA) * 256 + (((sl) ^ (swz)) * 16)))
#define FL(rowA, swz, sl) (*(const f16x8*)(lds + 32768 + (rowA) * 256 + (((sl) ^ (swz)) * 16)))

    for (int t = 0; t < 8; ++t) {
        f32x16 acc00 = zero16(), acc01 = zero16(), acc10 = zero16(), acc11 = zero16();
        const int n0 = t * 8 + wn * 2;     // 32-code block index, j in {0,1}

        // ---- pass 1+2: cross terms fh*wl' + fl'*wh (scaled by 2048) ----
#pragma unroll
        for (int ks = 0; ks < 8; ++ks) {
            const unsigned sl = (unsigned)(ks * 2 + lh);
            f16x8 wh0 = whv[((n0    ) * 8 + ks) * 64 + l];
            f16x8 wh1 = whv[((n0 + 1) * 8 + ks) * 64 + l];
            f16x8 wl0 = wlv[((n0    ) * 8 + ks) * 64 + l];
            f16x8 wl1 = wlv[((n0 + 1) * 8 + ks) * 64 + l];
            f16x8 fh0 = FH(rowA0, swz0, sl);
            f16x8 fh1 = FH(rowA1, swz1, sl);
            f16x8 fl0 = FL(rowA0, swz0, sl);
            f16x8 fl1 = FL(rowA1, swz1, sl);
            acc00 = MFMA(fh0, wl0, acc00);  acc00 = MFMA(fl0, wh0, acc00);
            acc01 = MFMA(fh0, wl1, acc01);  acc01 = MFMA(fl0, wh1, acc01);
            acc10 = MFMA(fh1, wl0, acc10);  acc10 = MFMA(fl1, wh0, acc10);
            acc11 = MFMA(fh1, wl1, acc11);  acc11 = MFMA(fl1, wh1, acc11);
        }
        const float inv2048 = 4.8828125e-4f;
        acc00 *= inv2048; acc01 *= inv2048; acc10 *= inv2048; acc11 *= inv2048;

        // ---- pass 3: hi*hi on top ----
#pragma unroll
        for (int ks = 0; ks < 8; ++ks) {
            const unsigned sl = (unsigned)(ks * 2 + lh);
            f16x8 wh0 = whv[((n0    ) * 8 + ks) * 64 + l];
            f16x8 wh1 = whv[((n0 + 1) * 8 + ks) * 64 + l];
            f16x8 fh0 = FH(rowA0, swz0, sl);
            f16x8 fh1 = FH(rowA1, swz1, sl);
            acc00 = MFMA(fh0, wh0, acc00);
            acc01 = MFMA(fh0, wh1, acc01);
            acc10 = MFMA(fh1, wh0, acc10);
            acc11 = MFMA(fh1, wh1, acc11);
        }

        // ---- fold into running argmin ----
        const int cbase = t * 256 + wn * 64 + l31;
        const float wn0 = wnorm[cbase];
        const float wn1 = wnorm[cbase + 32];
#pragma unroll
        for (int reg = 0; reg < 16; ++reg) {
            float s0 = fmaf(-2.0f, acc00[reg], wn0);
            float s1 = fmaf(-2.0f, acc01[reg], wn1);
            float s  = (s1 < s0) ? s1 : s0;
            int   c  = (s1 < s0) ? cbase + 32 : cbase;
            if (s < bestS[reg]) { bestS[reg] = s; bestC[reg] = c; }
            float u0 = fmaf(-2.0f, acc10[reg], wn0);
            float u1 = fmaf(-2.0f, acc11[reg], wn1);
            float us = (u1 < u0) ? u1 : u0;
            int   uc = (u1 < u0) ? cbase + 32 : cbase;
            if (us < bestS[16 + reg]) { bestS[16 + reg] = us; bestC[16 + reg] = uc; }
        }
    }

    // ---- cross-lane butterfly over the 32 code-columns ----
#pragma unroll
    for (int e = 0; e < 32; ++e) {
        float s = bestS[e];
        int   c = bestC[e];
#pragma unroll
        for (int m = 1; m <= 16; m <<= 1) {
            float s2 = __shfl_xor(s, m);
            int   c2 = __shfl_xor(c, m);
            if (s2 < s || (s2 == s && c2 < c)) { s = s2; c = c2; }
        }
        if (l31 == 0) {
            int reg = e & 15;
            int row = wm * 64 + (e >> 4) * 32 + (reg & 3) + 8 * (reg >> 2) + 4 * lh;
            redS[row * 4 + wn] = s;
            redC[row * 4 + wn] = c;
        }
    }
    __syncthreads();

    // ---- final fold across the 4 n-waves ----
    if (tid < MT) {
        float s = redS[tid * 4];
        int   c = redC[tid * 4];
#pragma unroll
        for (int v = 1; v < 4; ++v) {
            float s2 = redS[tid * 4 + v];
            int   c2 = redC[tid * 4 + v];
            if (s2 < s || (s2 == s && c2 < c)) { s = s2; c = c2; }
        }
        bestIdx[rowBase + tid] = c;
    }
#undef FH
#undef FL
}

// ---------------------------------------------------------------------------
// Kernel C: gather W[j], write out, per-batch loss (exact fp32).
// ---------------------------------------------------------------------------
__global__ void gather_kernel(const float* __restrict__ f, const float* __restrict__ W,
                              const int* __restrict__ bestIdx,
                              float* __restrict__ loss, float* __restrict__ outv) {
    int b  = blockIdx.x;
    int wv = threadIdx.x >> 6;
    int l  = threadIdx.x & 63;
    int n  = b * 4 + wv;
    int j  = bestIdx[n];
    float2 fv = reinterpret_cast<const float2*>(f + (size_t)n * D)[l];
    float2 wj = reinterpret_cast<const float2*>(W + (size_t)j * D)[l];
    reinterpret_cast<float2*>(outv + (size_t)n * D)[l] = wj;
    float dx = fv.x - wj.x, dy = fv.y - wj.y;
    float s = dx * dx + dy * dy;
#pragma unroll
    for (int off = 32; off; off >>= 1) s += __shfl_down(s, off);
    __shared__ float ls[4];
    if (l == 0) ls[wv] = s;
    __syncthreads();
    if (threadIdx.x == 0)
        loss[b] = 1.25f * 0.25f * (ls[0] + ls[1] + ls[2] + ls[3]);
}

// ---------------------------------------------------------------------------
extern "C" void kernel_launch(void* const* d_in, const int* in_sizes, int n_in,
                              void* d_out, int out_size, void* d_ws, size_t ws_size,
                              hipStream_t stream) {
    const float* f = (const float*)d_in[0];   // [8192,512] -> 32768 rows of 128
    const float* W = (const float*)d_in[1];   // [2048,128]

    float* loss = (float*)d_out;              // [8192]
    float* outv = (float*)d_out + BATCH;      // [8192*512]

    // workspace layout
    float*    wnorm   = (float*)d_ws;                                 //   8 KB
    int*      bestIdx = (int*)((char*)d_ws + 8192);                   // 128 KB
    _Float16* whf     = (_Float16*)((char*)d_ws + 139264);            // 512 KB
    _Float16* wlf     = (_Float16*)((char*)d_ws + 663552);            // 512 KB

    wconv_kernel<<<KCODES * 16 / 256, 256, 0, stream>>>(W, whf, wlf, wnorm);

    hipLaunchKernelGGL(vq_argmin, dim3(NROWS / MT), dim3(512), 69632, stream,
                       f, whf, wlf, wnorm, bestIdx);

    gather_kernel<<<BATCH, 256, 0, stream>>>(f, W, bestIdx, loss, outv);
}

// Round 3
// 111.352 us; speedup vs baseline: 3.0824x; 1.5343x over previous
//
#include <hip/hip_runtime.h>

#define D        128
#define KCODES   2048
#define NROWS    32768
#define BATCH    8192

typedef _Float16 f16x8  __attribute__((ext_vector_type(8)));
typedef float    f32x16 __attribute__((ext_vector_type(16)));

#define MFMA(a, b, c) __builtin_amdgcn_mfma_f32_32x32x16_f16((a), (b), (c), 0, 0, 0)
#define INV2048 4.8828125e-4f

static __device__ __forceinline__ f32x16 zero16() {
    f32x16 z;
#pragma unroll
    for (int i = 0; i < 16; ++i) z[i] = 0.0f;
    return z;
}

static __device__ __forceinline__ void gload16(const void* g, void* l) {
    __builtin_amdgcn_global_load_lds(
        (const __attribute__((address_space(1))) unsigned int*)g,
        (__attribute__((address_space(3))) unsigned int*)l, 16, 0, 0);
}

// ---------------------------------------------------------------------------
// Kernel A: W -> (wh, wl) fp16 hi/lo, fragment-linear layout + fp32 ||W||^2.
// Lane mapping (verified R2): for 32-code block n0, kstep ks, lane l holds
// W[n0*32 + (l&31)][ks*16 + (l>>5)*8 + j], stored at f16x8 idx ((n0*8+ks)*64+l).
// ---------------------------------------------------------------------------
__global__ void wconv_kernel(const float* __restrict__ W,
                             _Float16* __restrict__ whf, _Float16* __restrict__ wlf,
                             float* __restrict__ wnorm) {
    int gid = blockIdx.x * 256 + threadIdx.x;    // 32768 = 2048 codes x 16 slots
    int n = gid >> 4, s = gid & 15;
    const float4* src = (const float4*)(W + (size_t)n * D + s * 8);
    float4 a = src[0], b = src[1];
    float va[8] = {a.x, a.y, a.z, a.w, b.x, b.y, b.z, b.w};
    f16x8 hi, lo;
    float ss = 0.0f;
#pragma unroll
    for (int j = 0; j < 8; ++j) {
        _Float16 h = (_Float16)va[j];
        hi[j] = h;
        lo[j] = (_Float16)((va[j] - (float)h) * 2048.0f);
        ss += va[j] * va[j];
    }
    int ks = s >> 1, sub = s & 1;
    size_t idx = ((size_t)((n >> 5) * 8 + ks) * 64 + sub * 32 + (n & 31));
    ((f16x8*)whf)[idx] = hi;
    ((f16x8*)wlf)[idx] = lo;
#pragma unroll
    for (int m = 1; m <= 8; m <<= 1) ss += __shfl_xor(ss, m);
    if (s == 0) wnorm[n] = ss;
}

// ---------------------------------------------------------------------------
// Kernel B: fused MFMA scores + argmin, f-in-registers / W-through-LDS.
// Grid 256 = 128 row-blocks x 2 code-halves (XCD-partitioned: xcd = b&7,
// cH = (b&7)>>2, rb = (b>>3)*4 + (b&3) -- bijective, halves pinned to XCD sets).
// Block: 512 thr = 8 waves = 4 wm (64 rows each) x 2 wn (codes).
// Code half = 1024 codes in 8 chunks of 128; chunk staged hi+lo = 64 KB,
// double-buffered (128 KB LDS) via global_load_lds.
// Per chunk per wave: 32 ds_read_b128, 96 MFMA. Argmin meta nibble-packed.
// ---------------------------------------------------------------------------
extern "C" __global__ void __launch_bounds__(512, 2)
vq_argmin(const float* __restrict__ f,
          const _Float16* __restrict__ whf, const _Float16* __restrict__ wlf,
          const float* __restrict__ wnorm,
          float* __restrict__ bsp, int* __restrict__ bcp) {
    extern __shared__ unsigned char lds[];   // [2][65536] chunk dbuf; reduce reuses

    const int b   = blockIdx.x;
    const int cH  = (b & 7) >> 2;            // code half 0/1 -> XCD group
    const int rb  = (b >> 3) * 4 + (b & 3);  // row block 0..127
    const int tid = threadIdx.x;
    const int w   = tid >> 6, l = tid & 63;
    const int wm  = w >> 1, wn = w & 1;
    const int l31 = l & 31, lh = l >> 5;
    const int rowsBase = rb * 256 + wm * 64;

    // ---- stage chunk 0 while we convert A-frags ----
    {
        const char* gh = (const char*)whf + (size_t)(cH * 32) * 8192;
        const char* gl = (const char*)wlf + (size_t)(cH * 32) * 8192;
#pragma unroll
        for (int u = 0; u < 4; ++u) {
            gload16(gh + u * 8192 + tid * 16, lds + u * 8192 + tid * 16);
            gload16(gl + u * 8192 + tid * 16, lds + 32768 + u * 8192 + tid * 16);
        }
    }

    // ---- A-fragments: 64 rows of f in hi/lo fp16, registers (128 VGPR) ----
    f16x8 fh[2][8], fl[2][8];
#pragma unroll
    for (int mf = 0; mf < 2; ++mf) {
#pragma unroll
        for (int ks = 0; ks < 8; ++ks) {
            const float4* p = (const float4*)(f + (size_t)(rowsBase + mf * 32 + l31) * D
                                              + ks * 16 + lh * 8);
            float4 a = p[0], bb = p[1];
            float va[8] = {a.x, a.y, a.z, a.w, bb.x, bb.y, bb.z, bb.w};
            f16x8 hi, lo;
#pragma unroll
            for (int j = 0; j < 8; ++j) {
                _Float16 h = (_Float16)va[j];
                hi[j] = h;
                lo[j] = (_Float16)((va[j] - (float)h) * 2048.0f);
            }
            fh[mf][ks] = hi;
            fl[mf][ks] = lo;
        }
    }

    float    bestS[32];
    unsigned metaW[4] = {0u, 0u, 0u, 0u};    // 4-bit meta per entry: t*2+nf
#pragma unroll
    for (int e = 0; e < 32; ++e) bestS[e] = 3.4e38f;

    asm volatile("s_waitcnt vmcnt(0)");
    __syncthreads();

    for (int t = 0; t < 8; ++t) {
        if (t < 7) {   // issue next-chunk staging into other buffer
            const size_t go = (size_t)(cH * 32 + (t + 1) * 4) * 8192;
            unsigned char* dst = lds + ((t + 1) & 1) * 65536;
            const char* gh = (const char*)whf + go;
            const char* gl = (const char*)wlf + go;
#pragma unroll
            for (int u = 0; u < 4; ++u) {
                gload16(gh + u * 8192 + tid * 16, dst + u * 8192 + tid * 16);
                gload16(gl + u * 8192 + tid * 16, dst + 32768 + u * 8192 + tid * 16);
            }
        }
        const unsigned char* wb = lds + (t & 1) * 65536;

#pragma unroll
        for (int nf = 0; nf < 2; ++nf) {
            const int nl = wn * 2 + nf;      // chunk-local 32-code block
            f32x16 accC0 = zero16(), accH0 = zero16();
            f32x16 accC1 = zero16(), accH1 = zero16();
#pragma unroll
            for (int ks = 0; ks < 8; ++ks) {
                f16x8 wh = *(const f16x8*)(wb + (((nl * 8 + ks) * 64 + l) << 4));
                f16x8 wl = *(const f16x8*)(wb + 32768 + (((nl * 8 + ks) * 64 + l) << 4));
                accC0 = MFMA(fh[0][ks], wl, accC0);
                accC0 = MFMA(fl[0][ks], wh, accC0);
                accH0 = MFMA(fh[0][ks], wh, accH0);
                accC1 = MFMA(fh[1][ks], wl, accC1);
                accC1 = MFMA(fl[1][ks], wh, accC1);
                accH1 = MFMA(fh[1][ks], wh, accH1);
            }
            const int   col = cH * 1024 + t * 128 + nl * 32 + l31;
            const float wnv = wnorm[col];
            const unsigned mv = (unsigned)(t * 2 + nf);
#pragma unroll
            for (int r = 0; r < 16; ++r) {
                float s0 = fmaf(-2.0f, fmaf(accC0[r], INV2048, accH0[r]), wnv);
                if (s0 < bestS[r]) {
                    bestS[r] = s0;
                    metaW[r >> 3] = (metaW[r >> 3] & ~(0xFu << ((r & 7) * 4)))
                                    | (mv << ((r & 7) * 4));
                }
                float s1 = fmaf(-2.0f, fmaf(accC1[r], INV2048, accH1[r]), wnv);
                const int e = 16 + r;
                if (s1 < bestS[e]) {
                    bestS[e] = s1;
                    metaW[e >> 3] = (metaW[e >> 3] & ~(0xFu << ((e & 7) * 4)))
                                    | (mv << ((e & 7) * 4));
                }
            }
        }
        asm volatile("s_waitcnt vmcnt(0)");
        __syncthreads();
    }

    // ---- reduction: butterfly over 32 code-cols, then across wn pair ----
    float* redS = (float*)lds;               // [256][2]
    int*   redC = (int*)(lds + 2048);        // [256][2]
#pragma unroll
    for (int e = 0; e < 32; ++e) {
        float s = bestS[e];
        unsigned m = (metaW[e >> 3] >> ((e & 7) * 4)) & 0xFu;
        int c = cH * 1024 + (int)(m >> 1) * 128 + wn * 64 + (int)(m & 1) * 32 + l31;
#pragma unroll
        for (int msk = 1; msk <= 16; msk <<= 1) {
            float s2 = __shfl_xor(s, msk);
            int   c2 = __shfl_xor(c, msk);
            if (s2 < s || (s2 == s && c2 < c)) { s = s2; c = c2; }
        }
        if (l31 == 0) {
            int mf = e >> 4, r = e & 15;
            int row = wm * 64 + mf * 32 + (r & 3) + 8 * (r >> 2) + 4 * lh;
            redS[row * 2 + wn] = s;
            redC[row * 2 + wn] = c;
        }
    }
    __syncthreads();
    if (tid < 256) {
        float s0 = redS[tid * 2], s1 = redS[tid * 2 + 1];
        int   c0 = redC[tid * 2], c1 = redC[tid * 2 + 1];
        bool take1 = (s1 < s0) || (s1 == s0 && c1 < c0);
        bsp[(size_t)cH * NROWS + rb * 256 + tid] = take1 ? s1 : s0;
        bcp[(size_t)cH * NROWS + rb * 256 + tid] = take1 ? c1 : c0;
    }
}

// ---------------------------------------------------------------------------
// Kernel C: merge the two code-half partials, gather W[j], write out + loss.
// ---------------------------------------------------------------------------
__global__ void gather_kernel(const float* __restrict__ f, const float* __restrict__ W,
                              const float* __restrict__ bsp, const int* __restrict__ bcp,
                              float* __restrict__ loss, float* __restrict__ outv) {
    int b  = blockIdx.x;
    int wv = threadIdx.x >> 6;
    int l  = threadIdx.x & 63;
    int n  = b * 4 + wv;
    float s0 = bsp[n], s1 = bsp[NROWS + n];
    int   c0 = bcp[n], c1 = bcp[NROWS + n];
    int j = (s1 < s0) ? c1 : c0;   // tie -> c0 (always < c1)
    float2 fv = reinterpret_cast<const float2*>(f + (size_t)n * D)[l];
    float2 wj = reinterpret_cast<const float2*>(W + (size_t)j * D)[l];
    reinterpret_cast<float2*>(outv + (size_t)n * D)[l] = wj;
    float dx = fv.x - wj.x, dy = fv.y - wj.y;
    float s = dx * dx + dy * dy;
#pragma unroll
    for (int off = 32; off; off >>= 1) s += __shfl_down(s, off);
    __shared__ float ls[4];
    if (l == 0) ls[wv] = s;
    __syncthreads();
    if (threadIdx.x == 0)
        loss[b] = 1.25f * 0.25f * (ls[0] + ls[1] + ls[2] + ls[3]);
}

// ---------------------------------------------------------------------------
extern "C" void kernel_launch(void* const* d_in, const int* in_sizes, int n_in,
                              void* d_out, int out_size, void* d_ws, size_t ws_size,
                              hipStream_t stream) {
    const float* f = (const float*)d_in[0];   // [8192,512] -> 32768 rows of 128
    const float* W = (const float*)d_in[1];   // [2048,128]

    float* loss = (float*)d_out;              // [8192]
    float* outv = (float*)d_out + BATCH;      // [8192*512]

    // workspace layout
    float*    wnorm = (float*)d_ws;                              // @0       (8 KB)
    _Float16* whf   = (_Float16*)((char*)d_ws + 8192);           // @8K    (512 KB)
    _Float16* wlf   = (_Float16*)((char*)d_ws + 532480);         // @520K  (512 KB)
    float*    bsp   = (float*)((char*)d_ws + 1056768);           // @1032K (256 KB)
    int*      bcp   = (int*)((char*)d_ws + 1318912);             // @1288K (256 KB)

    wconv_kernel<<<KCODES * 16 / 256, 256, 0, stream>>>(W, whf, wlf, wnorm);

    hipLaunchKernelGGL(vq_argmin, dim3(256), dim3(512), 131072, stream,
                       f, whf, wlf, wnorm, bsp, bcp);

    gather_kernel<<<BATCH, 256, 0, stream>>>(f, W, bsp, bcp, loss, outv);
}

// Round 4
// 87.860 us; speedup vs baseline: 3.9066x; 1.2674x over previous
//
#include <hip/hip_runtime.h>

#define D        128
#define KCODES   2048
#define NROWS    32768
#define BATCH    8192

typedef _Float16 f16x8  __attribute__((ext_vector_type(8)));
typedef float    f32x16 __attribute__((ext_vector_type(16)));

#define MFMA(a, b, c) __builtin_amdgcn_mfma_f32_32x32x16_f16((a), (b), (c), 0, 0, 0)
#define INV2048 4.8828125e-4f

static __device__ __forceinline__ f32x16 zero16() {
    f32x16 z;
#pragma unroll
    for (int i = 0; i < 16; ++i) z[i] = 0.0f;
    return z;
}

static __device__ __forceinline__ void gload16(const void* g, void* l) {
    __builtin_amdgcn_global_load_lds(
        (const __attribute__((address_space(1))) unsigned int*)g,
        (__attribute__((address_space(3))) unsigned int*)l, 16, 0, 0);
}

// ---------------------------------------------------------------------------
// Kernel A: W -> (wh, wl) fp16 hi/lo, fragment-linear layout + fp32 ||W||^2.
// Lane mapping (verified R2/R3): for 32-code block n0, kstep ks, lane l holds
// W[n0*32 + (l&31)][ks*16 + (l>>5)*8 + j], stored at f16x8 idx ((n0*8+ks)*64+l).
// ---------------------------------------------------------------------------
__global__ void wconv_kernel(const float* __restrict__ W,
                             _Float16* __restrict__ whf, _Float16* __restrict__ wlf,
                             float* __restrict__ wnorm) {
    int gid = blockIdx.x * 256 + threadIdx.x;    // 32768 = 2048 codes x 16 slots
    int n = gid >> 4, s = gid & 15;
    const float4* src = (const float4*)(W + (size_t)n * D + s * 8);
    float4 a = src[0], b = src[1];
    float va[8] = {a.x, a.y, a.z, a.w, b.x, b.y, b.z, b.w};
    f16x8 hi, lo;
    float ss = 0.0f;
#pragma unroll
    for (int j = 0; j < 8; ++j) {
        _Float16 h = (_Float16)va[j];
        hi[j] = h;
        lo[j] = (_Float16)((va[j] - (float)h) * 2048.0f);
        ss += va[j] * va[j];
    }
    int ks = s >> 1, sub = s & 1;
    size_t idx = ((size_t)((n >> 5) * 8 + ks) * 64 + sub * 32 + (n & 31));
    ((f16x8*)whf)[idx] = hi;
    ((f16x8*)wlf)[idx] = lo;
#pragma unroll
    for (int m = 1; m <= 8; m <<= 1) ss += __shfl_xor(ss, m);
    if (s == 0) wnorm[n] = ss;
}

// ---------------------------------------------------------------------------
// Kernel B: fused MFMA scores + argmin, f-in-registers / W-through-LDS.
// Grid 256 = 128 row-blocks x 2 code-halves (XCD-partitioned).
// Block: 512 thr = 8 waves = 4 wm (64 rows each) x 2 wn.
// Single-accumulator 3-pass: acc = cross; acc *= 2^-11; acc += hi*hi (MFMA
// C-input carries the scaled partial).  wh cached in regs across both loops.
// Reg budget ~240 of 256 (waves_per_eu pinned to 2).
// ---------------------------------------------------------------------------
extern "C" __global__ void __launch_bounds__(512)
__attribute__((amdgpu_flat_work_group_size(512, 512)))
__attribute__((amdgpu_waves_per_eu(2, 2)))
vq_argmin(const float* __restrict__ f,
          const _Float16* __restrict__ whf, const _Float16* __restrict__ wlf,
          const float* __restrict__ wnorm,
          float* __restrict__ bsp, int* __restrict__ bcp) {
    extern __shared__ unsigned char lds[];   // [2][65536] chunk dbuf; reduce reuses

    const int b   = blockIdx.x;
    const int cH  = (b & 7) >> 2;            // code half 0/1 -> XCD group
    const int rb  = (b >> 3) * 4 + (b & 3);  // row block 0..127
    const int tid = threadIdx.x;
    const int w   = tid >> 6, l = tid & 63;
    const int wm  = w >> 1, wn = w & 1;
    const int l31 = l & 31, lh = l >> 5;
    const int rowsBase = rb * 256 + wm * 64;

    // ---- stage chunk 0 while we convert A-frags ----
    {
        const char* gh = (const char*)whf + (size_t)(cH * 32) * 8192;
        const char* gl = (const char*)wlf + (size_t)(cH * 32) * 8192;
#pragma unroll
        for (int u = 0; u < 4; ++u) {
            gload16(gh + u * 8192 + tid * 16, lds + u * 8192 + tid * 16);
            gload16(gl + u * 8192 + tid * 16, lds + 32768 + u * 8192 + tid * 16);
        }
    }

    // ---- A-fragments: 64 rows of f in hi/lo fp16, registers (128 VGPR) ----
    f16x8 fh[2][8], fl[2][8];
#pragma unroll
    for (int mf = 0; mf < 2; ++mf) {
#pragma unroll
        for (int ks = 0; ks < 8; ++ks) {
            const float4* p = (const float4*)(f + (size_t)(rowsBase + mf * 32 + l31) * D
                                              + ks * 16 + lh * 8);
            float4 a = p[0], bb = p[1];
            float va[8] = {a.x, a.y, a.z, a.w, bb.x, bb.y, bb.z, bb.w};
            f16x8 hi, lo;
#pragma unroll
            for (int j = 0; j < 8; ++j) {
                _Float16 h = (_Float16)va[j];
                hi[j] = h;
                lo[j] = (_Float16)((va[j] - (float)h) * 2048.0f);
            }
            fh[mf][ks] = hi;
            fl[mf][ks] = lo;
        }
    }

    float    bestS[32];
    unsigned metaW[4] = {0u, 0u, 0u, 0u};    // 4-bit meta per entry: t*2+nf
#pragma unroll
    for (int e = 0; e < 32; ++e) bestS[e] = 3.4e38f;

    asm volatile("s_waitcnt vmcnt(0)");
    __syncthreads();

    for (int t = 0; t < 8; ++t) {
        if (t < 7) {   // issue next-chunk staging into other buffer
            const size_t go = (size_t)(cH * 32 + (t + 1) * 4) * 8192;
            unsigned char* dst = lds + ((t + 1) & 1) * 65536;
            const char* gh = (const char*)whf + go;
            const char* gl = (const char*)wlf + go;
#pragma unroll
            for (int u = 0; u < 4; ++u) {
                gload16(gh + u * 8192 + tid * 16, dst + u * 8192 + tid * 16);
                gload16(gl + u * 8192 + tid * 16, dst + 32768 + u * 8192 + tid * 16);
            }
        }
        const unsigned char* wb = lds + (t & 1) * 65536;

#pragma unroll
        for (int nf = 0; nf < 2; ++nf) {
            const int nl = wn * 2 + nf;      // chunk-local 32-code block
            const int col = cH * 1024 + t * 128 + nl * 32 + l31;
            const float wnv = wnorm[col];

            f16x8  whc[8];
            f32x16 a0 = zero16(), a1 = zero16();

            // pass 1+2: cross terms (scaled by 2048), cache wh
#pragma unroll
            for (int ks = 0; ks < 8; ++ks) {
                whc[ks]  = *(const f16x8*)(wb + (((nl * 8 + ks) * 64 + l) << 4));
                f16x8 wl = *(const f16x8*)(wb + 32768 + (((nl * 8 + ks) * 64 + l) << 4));
                a0 = MFMA(fh[0][ks], wl, a0);
                a0 = MFMA(fl[0][ks], whc[ks], a0);
                a1 = MFMA(fh[1][ks], wl, a1);
                a1 = MFMA(fl[1][ks], whc[ks], a1);
            }
            // scale cross partial into fp32-domain
#pragma unroll
            for (int r = 0; r < 16; ++r) { a0[r] *= INV2048; a1[r] *= INV2048; }
            // pass 3: hi*hi accumulated on top (C-input carries partial)
#pragma unroll
            for (int ks = 0; ks < 8; ++ks) {
                a0 = MFMA(fh[0][ks], whc[ks], a0);
                a1 = MFMA(fh[1][ks], whc[ks], a1);
            }

            // fold into running argmin
            const unsigned mv = (unsigned)(t * 2 + nf);
#pragma unroll
            for (int r = 0; r < 16; ++r) {
                float s0 = fmaf(-2.0f, a0[r], wnv);
                if (s0 < bestS[r]) {
                    bestS[r] = s0;
                    metaW[r >> 3] = (metaW[r >> 3] & ~(0xFu << ((r & 7) * 4)))
                                    | (mv << ((r & 7) * 4));
                }
                float s1 = fmaf(-2.0f, a1[r], wnv);
                const int e = 16 + r;
                if (s1 < bestS[e]) {
                    bestS[e] = s1;
                    metaW[e >> 3] = (metaW[e >> 3] & ~(0xFu << ((e & 7) * 4)))
                                    | (mv << ((e & 7) * 4));
                }
            }
        }
        asm volatile("s_waitcnt vmcnt(0)");
        __syncthreads();
    }

    // ---- reduction: butterfly over 32 code-cols, then across wn pair ----
    float* redS = (float*)lds;               // [256][2]
    int*   redC = (int*)(lds + 2048);        // [256][2]
#pragma unroll
    for (int e = 0; e < 32; ++e) {
        float s = bestS[e];
        unsigned m = (metaW[e >> 3] >> ((e & 7) * 4)) & 0xFu;
        int c = cH * 1024 + (int)(m >> 1) * 128 + wn * 64 + (int)(m & 1) * 32 + l31;
#pragma unroll
        for (int msk = 1; msk <= 16; msk <<= 1) {
            float s2 = __shfl_xor(s, msk);
            int   c2 = __shfl_xor(c, msk);
            if (s2 < s || (s2 == s && c2 < c)) { s = s2; c = c2; }
        }
        if (l31 == 0) {
            int mf = e >> 4, r = e & 15;
            int row = wm * 64 + mf * 32 + (r & 3) + 8 * (r >> 2) + 4 * lh;
            redS[row * 2 + wn] = s;
            redC[row * 2 + wn] = c;
        }
    }
    __syncthreads();
    if (tid < 256) {
        float s0 = redS[tid * 2], s1 = redS[tid * 2 + 1];
        int   c0 = redC[tid * 2], c1 = redC[tid * 2 + 1];
        bool take1 = (s1 < s0) || (s1 == s0 && c1 < c0);
        bsp[(size_t)cH * NROWS + rb * 256 + tid] = take1 ? s1 : s0;
        bcp[(size_t)cH * NROWS + rb * 256 + tid] = take1 ? c1 : c0;
    }
}

// ---------------------------------------------------------------------------
// Kernel C: merge the two code-half partials, gather W[j], write out + loss.
// ---------------------------------------------------------------------------
__global__ void gather_kernel(const float* __restrict__ f, const float* __restrict__ W,
                              const float* __restrict__ bsp, const int* __restrict__ bcp,
                              float* __restrict__ loss, float* __restrict__ outv) {
    int b  = blockIdx.x;
    int wv = threadIdx.x >> 6;
    int l  = threadIdx.x & 63;
    int n  = b * 4 + wv;
    float s0 = bsp[n], s1 = bsp[NROWS + n];
    int   c0 = bcp[n], c1 = bcp[NROWS + n];
    int j = (s1 < s0) ? c1 : c0;   // tie -> c0 (always < c1)
    float2 fv = reinterpret_cast<const float2*>(f + (size_t)n * D)[l];
    float2 wj = reinterpret_cast<const float2*>(W + (size_t)j * D)[l];
    reinterpret_cast<float2*>(outv + (size_t)n * D)[l] = wj;
    float dx = fv.x - wj.x, dy = fv.y - wj.y;
    float s = dx * dx + dy * dy;
#pragma unroll
    for (int off = 32; off; off >>= 1) s += __shfl_down(s, off);
    __shared__ float ls[4];
    if (l == 0) ls[wv] = s;
    __syncthreads();
    if (threadIdx.x == 0)
        loss[b] = 1.25f * 0.25f * (ls[0] + ls[1] + ls[2] + ls[3]);
}

// ---------------------------------------------------------------------------
extern "C" void kernel_launch(void* const* d_in, const int* in_sizes, int n_in,
                              void* d_out, int out_size, void* d_ws, size_t ws_size,
                              hipStream_t stream) {
    const float* f = (const float*)d_in[0];   // [8192,512] -> 32768 rows of 128
    const float* W = (const float*)d_in[1];   // [2048,128]

    float* loss = (float*)d_out;              // [8192]
    float* outv = (float*)d_out + BATCH;      // [8192*512]

    // workspace layout
    float*    wnorm = (float*)d_ws;                              // @0       (8 KB)
    _Float16* whf   = (_Float16*)((char*)d_ws + 8192);           // @8K    (512 KB)
    _Float16* wlf   = (_Float16*)((char*)d_ws + 532480);         // @520K  (512 KB)
    float*    bsp   = (float*)((char*)d_ws + 1056768);           // @1032K (256 KB)
    int*      bcp   = (int*)((char*)d_ws + 1318912);             // @1288K (256 KB)

    wconv_kernel<<<KCODES * 16 / 256, 256, 0, stream>>>(W, whf, wlf, wnorm);

    hipLaunchKernelGGL(vq_argmin, dim3(256), dim3(512), 131072, stream,
                       f, whf, wlf, wnorm, bsp, bcp);

    gather_kernel<<<BATCH, 256, 0, stream>>>(f, W, bsp, bcp, loss, outv);
}